// Round 8
// baseline (330.207 us; speedup 1.0000x reference)
//
#include <hip/hip_runtime.h>

#define THREADS 256

typedef __attribute__((ext_vector_type(8))) short bf16x8;
typedef __attribute__((ext_vector_type(4))) float f32x4;
typedef __attribute__((ext_vector_type(2))) float f32x2;
typedef __attribute__((ext_vector_type(4))) int i32x4;

#define CNT_SHIFT 20
#define DEG_SCALE 8192.0f              // 2^13 fixed-point for weighted degree
#define DEG_MASK  ((1u << CNT_SHIFT) - 1)

__device__ inline float bf2f(unsigned short u) {
    union { unsigned int i; float f; } v; v.i = ((unsigned int)u) << 16; return v.f;
}
__device__ inline unsigned short f2bf(float f) {
    union { float f; unsigned int i; } v; v.f = f;
    unsigned int i = v.i;
    i += 0x7fff + ((i >> 16) & 1);   // round-to-nearest-even
    return (unsigned short)(i >> 16);
}

// ---------- fat kernel 1: weight prep (blocks [0,513)) ∥ edge count (rest) ----
// count: one 32-bit atomic per edge: count in [20:31], fixed-point deg in [0:19];
// returned old value = edge's rank within its dst (free CSR slot).
__global__ void k_cvt_count(const float* __restrict__ W1, const float* __restrict__ Wmu,
                            const float* __restrict__ Wls, const float* __restrict__ bmu,
                            const float* __restrict__ bls,
                            ushort* __restrict__ W1t, ushort* __restrict__ Wct,
                            float* __restrict__ bcat,
                            const int* __restrict__ dst, const float* __restrict__ ew,
                            unsigned int* __restrict__ packed,
                            int* __restrict__ rank, int E) {
    int nb = blockIdx.x, k = threadIdx.x;
    if (nb < 256) {
        W1t[k * 256 + nb] = f2bf(W1[nb * 256 + k]);
    } else if (nb < 512) {
        int r = nb - 256;              // dh row index
        float v = (k < 128) ? Wmu[r * 128 + k] : Wls[r * 128 + (k - 128)];
        Wct[k * 256 + r] = f2bf(v);
    } else if (nb == 512) {
        bcat[k] = (k < 128) ? bmu[k] : bls[k - 128];
    } else {
        int e = (nb - 513) * THREADS + k;
        if (e >= E) return;
        int c = __builtin_nontemporal_load(dst + e);
        float w = __builtin_nontemporal_load(ew + e);
        unsigned int v = (1u << CNT_SHIFT) | (unsigned int)(w * DEG_SCALE + 0.5f);
        unsigned int old = atomicAdd(&packed[c], v);
        __builtin_nontemporal_store((int)(old >> CNT_SHIFT), rank + e);
    }
}

// ---------- exclusive prefix scan over counts (fused unpack: counts + dinv) ----------
__global__ void k_scan_part(const unsigned int* __restrict__ packed,
                            int* __restrict__ counts, float* __restrict__ dinv,
                            int* __restrict__ offsets, int* __restrict__ blocksum, int n) {
    __shared__ int s[THREADS];
    int i = blockIdx.x * THREADS + threadIdx.x;
    unsigned int p = (i < n) ? packed[i] : 0u;
    int v = (int)(p >> CNT_SHIFT);
    if (i < n) {
        counts[i] = v;
        float d = 1.0f + (float)(p & DEG_MASK) * (1.0f / DEG_SCALE);
        dinv[i] = rsqrtf(d);           // d >= 1 always
    }
    s[threadIdx.x] = v;
    __syncthreads();
    for (int d = 1; d < THREADS; d <<= 1) {
        int t = (threadIdx.x >= d) ? s[threadIdx.x - d] : 0;
        __syncthreads();
        s[threadIdx.x] += t;
        __syncthreads();
    }
    if (i < n) offsets[i] = s[threadIdx.x] - v;
    if (threadIdx.x == THREADS - 1) blocksum[blockIdx.x] = s[THREADS - 1];
}

__global__ void k_scan_block(int* __restrict__ blocksum, int nb) {
    __shared__ int s[THREADS];
    int v = (threadIdx.x < nb) ? blocksum[threadIdx.x] : 0;
    s[threadIdx.x] = v;
    __syncthreads();
    for (int d = 1; d < THREADS; d <<= 1) {
        int t = (threadIdx.x >= d) ? s[threadIdx.x - d] : 0;
        __syncthreads();
        s[threadIdx.x] += t;
        __syncthreads();
    }
    if (threadIdx.x < nb) blocksum[threadIdx.x] = s[threadIdx.x] - v;
}

// ---------- aggregation, feature-split two-pass: out[i] = bias + dinv_i^2*f[i]
//            + sum_e norm_e*f[src_e]
// Blocks [0,nbh) handle features 0..127 (half 0); [nbh,2nbh) features 128..255.
// Dispatch order separates the passes in time, halving the active gather
// working set (12.8 MB vs 25.6 MB of distinct lines) -> higher L2 hit rate on
// the fixed ~16x/row reuse -> less L2-miss fabric traffic (the binder).
// One wave per node per half; lane covers 2 features (4 B).
// MODE 0: +bias, relu, bf16 out.  MODE 1: half0 -> mu, half1 -> logstd (f32).
template<int MODE>
__global__ void k_agg(const unsigned int* __restrict__ fb,
                      const int* __restrict__ eoff, const int* __restrict__ ecnt,
                      const int* __restrict__ bsum,
                      const int2* __restrict__ epack, const float* __restrict__ dinv,
                      const float* __restrict__ bias, void* __restrict__ out,
                      int n, int nbh) {
    int wave = threadIdx.x >> 6, lane = threadIdx.x & 63;
    int half = (blockIdx.x >= nbh) ? 1 : 0;
    int node = (blockIdx.x - half * nbh) * 4 + wave;
    if (node >= n) return;
    int h64 = half * 64;
    float ds = dinv[node]; ds *= ds;        // self-loop norm
    unsigned int v = fb[(size_t)node * 128 + h64 + lane];
    float ax = ds * bf2f((ushort)v), ay = ds * bf2f((ushort)(v >> 16));
    int e = eoff[node] + bsum[node >> 8], cnt = ecnt[node];
    while (cnt > 0) {
        int take = cnt < 64 ? cnt : 64;
        int2 meta = make_int2(0, 0);          // padded lanes: src=0, w=0
        if (lane < take) {
            long long m = __builtin_nontemporal_load((const long long*)&epack[e + lane]);
            meta.x = (int)m; meta.y = (int)(m >> 32);
        }
        for (int j = 0; j < take; j += 8) {
            int s0 = __builtin_amdgcn_readlane(meta.x, j + 0);
            int s1 = __builtin_amdgcn_readlane(meta.x, j + 1);
            int s2 = __builtin_amdgcn_readlane(meta.x, j + 2);
            int s3 = __builtin_amdgcn_readlane(meta.x, j + 3);
            int s4 = __builtin_amdgcn_readlane(meta.x, j + 4);
            int s5 = __builtin_amdgcn_readlane(meta.x, j + 5);
            int s6 = __builtin_amdgcn_readlane(meta.x, j + 6);
            int s7 = __builtin_amdgcn_readlane(meta.x, j + 7);
            float w0 = __int_as_float(__builtin_amdgcn_readlane(meta.y, j + 0));
            float w1 = __int_as_float(__builtin_amdgcn_readlane(meta.y, j + 1));
            float w2 = __int_as_float(__builtin_amdgcn_readlane(meta.y, j + 2));
            float w3 = __int_as_float(__builtin_amdgcn_readlane(meta.y, j + 3));
            float w4 = __int_as_float(__builtin_amdgcn_readlane(meta.y, j + 4));
            float w5 = __int_as_float(__builtin_amdgcn_readlane(meta.y, j + 5));
            float w6 = __int_as_float(__builtin_amdgcn_readlane(meta.y, j + 6));
            float w7 = __int_as_float(__builtin_amdgcn_readlane(meta.y, j + 7));
            unsigned int u0 = fb[(size_t)s0 * 128 + h64 + lane];
            unsigned int u1 = fb[(size_t)s1 * 128 + h64 + lane];
            unsigned int u2 = fb[(size_t)s2 * 128 + h64 + lane];
            unsigned int u3 = fb[(size_t)s3 * 128 + h64 + lane];
            unsigned int u4 = fb[(size_t)s4 * 128 + h64 + lane];
            unsigned int u5 = fb[(size_t)s5 * 128 + h64 + lane];
            unsigned int u6 = fb[(size_t)s6 * 128 + h64 + lane];
            unsigned int u7 = fb[(size_t)s7 * 128 + h64 + lane];
            ax += w0 * bf2f((ushort)u0) + w1 * bf2f((ushort)u1)
                + w2 * bf2f((ushort)u2) + w3 * bf2f((ushort)u3);
            ay += w0 * bf2f((ushort)(u0 >> 16)) + w1 * bf2f((ushort)(u1 >> 16))
                + w2 * bf2f((ushort)(u2 >> 16)) + w3 * bf2f((ushort)(u3 >> 16));
            ax += w4 * bf2f((ushort)u4) + w5 * bf2f((ushort)u5)
                + w6 * bf2f((ushort)u6) + w7 * bf2f((ushort)u7);
            ay += w4 * bf2f((ushort)(u4 >> 16)) + w5 * bf2f((ushort)(u5 >> 16))
                + w6 * bf2f((ushort)(u6 >> 16)) + w7 * bf2f((ushort)(u7 >> 16));
        }
        e += take; cnt -= take;
    }
    float2 b = ((const float2*)bias)[h64 + lane];
    ax += b.x; ay += b.y;
    if (MODE == 0) {
        unsigned int o = (unsigned int)f2bf(fmaxf(ax, 0.f))
                       | ((unsigned int)f2bf(fmaxf(ay, 0.f)) << 16);
        __builtin_nontemporal_store(o,
            (unsigned int*)out + (size_t)node * 128 + h64 + lane);
    } else {
        f32x2 o; o[0] = ax; o[1] = ay;
        // half 0 -> mu[n][128], half 1 -> logstd[n][128] (f32, 64 float2/node)
        f32x2* dst = (f32x2*)out + (size_t)half * n * 64;
        __builtin_nontemporal_store(o, &dst[(size_t)node * 64 + lane]);
    }
}

// ---------- bf16 MFMA GEMM body: C[Mx256] = A[Mx256] @ Bt[256x256]^T, bf16 out
// 8 waves, BM=128 x BN=256 (full width) -> A is read exactly once.
// AF32: A is f32, converted to bf16 during LDS staging (nt loads: A streamed once).
#define LDT 40   // padded LDS row stride (ushorts): <=2-way bank aliasing (free, m136)
template<int AF32>
__device__ __forceinline__ void gemm_body(const void* __restrict__ Ain,
        const ushort* __restrict__ Bt, ushort* __restrict__ C, int M, int bid) {
    __shared__ ushort As[128 * LDT];
    __shared__ ushort Bs[256 * LDT];
    const float*  Af = (const float*)Ain;
    const ushort* Ab = (const ushort*)Ain;
    int tid = threadIdx.x;
    int lane = tid & 63, wave = tid >> 6;
    int row0 = bid * 128;
    int mw = (wave >> 2) * 64, nw = (wave & 3) * 64;
    int lr = lane & 15, lq = lane >> 4;
    f32x4 acc[4][4] = {};
    for (int k0 = 0; k0 < 256; k0 += 32) {
        {   // stage A: one 8-elem chunk per thread (512 chunks total)
            int r = tid >> 2, q = tid & 3;
            int gr = row0 + r;
            i32x4 av = {0, 0, 0, 0};
            if (gr < M) {
                if (AF32) {
                    const float* p = Af + (size_t)gr * 256 + k0 + q * 8;
                    i32x4 lo = __builtin_nontemporal_load((const i32x4*)p);
                    i32x4 hi = __builtin_nontemporal_load((const i32x4*)(p + 4));
                    ushort* u = (ushort*)&av;
                    u[0] = f2bf(__int_as_float(lo[0])); u[1] = f2bf(__int_as_float(lo[1]));
                    u[2] = f2bf(__int_as_float(lo[2])); u[3] = f2bf(__int_as_float(lo[3]));
                    u[4] = f2bf(__int_as_float(hi[0])); u[5] = f2bf(__int_as_float(hi[1]));
                    u[6] = f2bf(__int_as_float(hi[2])); u[7] = f2bf(__int_as_float(hi[3]));
                } else {
                    av = __builtin_nontemporal_load(
                        (const i32x4*)(Ab + (size_t)gr * 256 + k0 + q * 8));
                }
            }
            *(i32x4*)(&As[r * LDT + q * 8]) = av;
        }
        #pragma unroll
        for (int i = 0; i < 2; i++) {   // stage B: 1024 chunks, 2 per thread
            int c = tid + i * 512;
            int r = c >> 2, q = c & 3;
            i32x4 bv = *(const i32x4*)(Bt + (size_t)r * 256 + k0 + q * 8);
            *(i32x4*)(&Bs[r * LDT + q * 8]) = bv;
        }
        __syncthreads();
        bf16x8 af[4], bfr[4];
        #pragma unroll
        for (int mi = 0; mi < 4; mi++)
            af[mi] = *(const bf16x8*)(&As[(mw + mi * 16 + lr) * LDT + lq * 8]);
        #pragma unroll
        for (int ni = 0; ni < 4; ni++)
            bfr[ni] = *(const bf16x8*)(&Bs[(nw + ni * 16 + lr) * LDT + lq * 8]);
        #pragma unroll
        for (int mi = 0; mi < 4; mi++)
            #pragma unroll
            for (int ni = 0; ni < 4; ni++)
                acc[mi][ni] = __builtin_amdgcn_mfma_f32_16x16x32_bf16(
                    af[mi], bfr[ni], acc[mi][ni], 0, 0, 0);
        __syncthreads();
    }
    // C/D layout: col = lane&15, row = (lane>>4)*4 + reg
    #pragma unroll
    for (int mi = 0; mi < 4; mi++)
        #pragma unroll
        for (int ni = 0; ni < 4; ni++)
            #pragma unroll
            for (int r = 0; r < 4; r++) {
                int grow = row0 + mw + mi * 16 + lq * 4 + r;
                int gcol = nw + ni * 16 + lr;
                if (grow < M) C[(size_t)grow * 256 + gcol] = f2bf(acc[mi][ni][r]);
            }
}

template<int AF32>
__global__ __launch_bounds__(512) void k_gemm(const void* __restrict__ Ain,
        const ushort* __restrict__ Bt, ushort* __restrict__ C, int M) {
    gemm_body<AF32>(Ain, Bt, C, M, blockIdx.x);
}

// ---------- fat kernel 2: gemm1 (blocks [0, nGemm)) ∥ CSR fill (rest) ----------
// fill is atomic-free: pos = offsets[dst] + bsum[dst/256] + rank; cached scatter
// (each 64B line gets ~8 edge-writes that coalesce in L2/MALL).
__global__ __launch_bounds__(512) void k_gemm1_fill(
        const float* __restrict__ x, const ushort* __restrict__ W1t,
        ushort* __restrict__ C, int M, int nGemm,
        const int* __restrict__ ei, const float* __restrict__ ew,
        const float* __restrict__ dinv, const int* __restrict__ offsets,
        const int* __restrict__ bsum, const int* __restrict__ rank,
        int2* __restrict__ epack, int E) {
    int bid = blockIdx.x;
    if (bid < nGemm) {
        gemm_body<1>(x, W1t, C, M, bid);
        return;
    }
    int e = (bid - nGemm) * 512 + threadIdx.x;
    if (e >= E) return;
    int r = __builtin_nontemporal_load(ei + e);
    int c = __builtin_nontemporal_load(ei + E + e);
    float w = __builtin_nontemporal_load(ew + e);
    int rk = __builtin_nontemporal_load(rank + e);
    int pos = offsets[c] + bsum[c >> 8] + rk;
    long long m = (long long)r |
        ((long long)__float_as_int(dinv[r] * w * dinv[c]) << 32);
    *(long long*)&epack[pos] = m;      // cached scatter (see note above)
}

extern "C" void kernel_launch(void* const* d_in, const int* in_sizes, int n_in,
                              void* d_out, int out_size, void* d_ws, size_t ws_size,
                              hipStream_t stream) {
    const float* x   = (const float*)d_in[0];
    const int*   ei  = (const int*)d_in[1];
    const float* ew  = (const float*)d_in[2];
    const float* W1  = (const float*)d_in[3];
    const float* b1  = (const float*)d_in[4];
    const float* Wmu = (const float*)d_in[5];
    const float* bmu = (const float*)d_in[6];
    const float* Wls = (const float*)d_in[7];
    const float* bls = (const float*)d_in[8];

    const int DIN = 256;
    const int N = in_sizes[0] / DIN;
    const int E = in_sizes[2];

    // workspace layout
    unsigned int* packed = (unsigned int*)d_ws;       // N
    int*   counts   = (int*)(packed + N);             // N
    int*   offsets  = counts + N;                     // N
    float* dinv     = (float*)(offsets + N);          // N
    int*   blocksum = (int*)(dinv + N);               // 256
    int*   rank     = blocksum + 256;                 // E
    int2*  epack    = (int2*)(rank + E);              // E
    ushort* xw      = (ushort*)(epack + E);           // N*256  (x@W1, bf16)
    ushort* hb      = xw + (size_t)N * 256;           // N*256  (h, bf16)
    ushort* hw      = hb + (size_t)N * 256;           // N*256  (h@Wct, bf16)
    ushort* W1t     = hw + (size_t)N * 256;           // 256*256
    ushort* Wct     = W1t + 256 * 256;                // 256*256
    float*  bcat    = (float*)(Wct + 256 * 256);      // 256

    int gN = (N + THREADS - 1) / THREADS;

    // zero packed (async, graph-capturable), then [weight prep ∥ edge count]
    hipMemsetAsync(packed, 0, (size_t)N * sizeof(unsigned int), stream);

    int nCnt = (E + THREADS - 1) / THREADS;
    k_cvt_count<<<513 + nCnt, THREADS, 0, stream>>>(W1, Wmu, Wls, bmu, bls,
                                                    W1t, Wct, bcat,
                                                    ei + E, ew, packed, rank, E);

    k_scan_part<<<gN, THREADS, 0, stream>>>(packed, counts, dinv, offsets, blocksum, N);
    k_scan_block<<<1, THREADS, 0, stream>>>(blocksum, gN);

    int nGemm = (N + 127) / 128;
    int nFill = (E + 511) / 512;

    // [layer-1 GEMM (xw = x@W1) ∥ CSR fill] — independent after the scan
    k_gemm1_fill<<<nGemm + nFill, 512, 0, stream>>>(x, W1t, xw, N, nGemm,
                                                    ei, ew, dinv, offsets,
                                                    blocksum, rank, epack, E);

    int nbh = (N + 3) / 4;

    // layer 1 agg: h = relu(A_hat@xw + b1)  (two feature-half passes, one launch)
    k_agg<0><<<nbh * 2, THREADS, 0, stream>>>((const unsigned int*)xw, offsets, counts,
                                              blocksum, epack, dinv, b1, hb, N, nbh);

    // layer 2: hw = h@[Wmu|Wls];  {mu,logstd} = A_hat@hw + bcat
    k_gemm<0><<<nGemm, 512, 0, stream>>>(hb, Wct, hw, N);
    k_agg<1><<<nbh * 2, THREADS, 0, stream>>>((const unsigned int*)hw, offsets, counts,
                                              blocksum, epack, dinv, bcat, d_out, N, nbh);
}